// Round 3
// baseline (343.736 us; speedup 1.0000x reference)
//
#include <hip/hip_runtime.h>
#include <hip/hip_bf16.h>

// MultiScaleAttentionPE — MI355X round 6
// Round-4 fold kept: pe = peB[k] @ P_top (bf16 MFMA, K=256)
//                       + dxyz @ (W@P_top) + xyz @ (Wall@P_bot) + c   (fp32 exact)
// Round-6: level_mfma goes LDS-free — A/B MFMA fragments are contiguous 16B
// chunks in peB_prev / PT, loaded directly global->VGPR. Zero k-loop barriers;
// fully unrolled K so loads pipeline across MFMA (counted-vmcnt by compiler).

typedef __hip_bfloat16 bf16;
typedef unsigned short ushort_t;
typedef __attribute__((ext_vector_type(8))) short short8;
typedef __attribute__((ext_vector_type(4))) float float4v;

#define cN0 65536
#define cN1 16384
#define cN2 4096
#define cN3 1024
#define cN4 256

__device__ __forceinline__ float b2f(bf16 v) { return __bfloat162float(v); }

// RNE float -> bf16 bits (values are finite; no NaN path needed)
__device__ __forceinline__ ushort_t f2b(float v) {
    union { float f; unsigned u; } x; x.f = v;
    unsigned r = x.u + 0x7FFF + ((x.u >> 16) & 1);
    return (ushort_t)(r >> 16);
}

// ---------------- dtype detect (bf16 vs fp32 storage) ----------------
__global__ void detect_kernel(const unsigned short* __restrict__ raw, int* __restrict__ flag) {
    __shared__ int bad;
    if (threadIdx.x == 0) bad = 0;
    __syncthreads();
    for (int i = threadIdx.x; i < 1024; i += 256) {
        int e = (raw[i] >> 7) & 0xFF;
        if (e >= 138) atomicOr(&bad, 1);
    }
    __syncthreads();
    if (threadIdx.x == 0) flag[0] = bad ? 1 : 0;
}

// ---------------- canonicalize all float tensors to fp32 ----------------
struct CanonArgs { const void* src[23]; };

__global__ void canon_kernel(CanonArgs a, const int* __restrict__ flag, float* __restrict__ dst) {
    const int sizes[23] = {196608, 768, 256,
                           768, 256, 768, 256, 768, 256, 768, 256, 768, 256,
                           131072, 256, 131072, 256, 131072, 256, 131072, 256, 131072, 256};
    int fp32 = flag[0];
    int gid = blockIdx.x * 256 + threadIdx.x;
    int off = 0;
#pragma unroll
    for (int s = 0; s < 23; ++s) {
        int n = sizes[s];
        if (gid >= off && gid < off + n) {
            int local = gid - off;
            float v = fp32 ? ((const float*)a.src[s])[local]
                           : b2f(((const bf16*)a.src[s])[local]);
            dst[gid] = v;
        }
        off += n;
    }
}

// ---------------- P_top -> P_top^T bf16  ([256][256] of the [512][256] fp32) ----------------
__global__ void prep_pt(const float* __restrict__ Pf0, ushort_t* __restrict__ PTb) {
    int level = blockIdx.x;
    int kb = blockIdx.y;
    int nb = blockIdx.z;
    const float* P = Pf0 + (size_t)level * 131328;   // P (131072) + pb (256) stride
    ushort_t* PT = PTb + (size_t)level * 65536;
    __shared__ float tile[64][65];
    int tx = threadIdx.x & 63, ty = threadIdx.x >> 6;
    for (int r = ty; r < 64; r += 4)
        tile[r][tx] = P[(size_t)(kb * 64 + r) * 256 + nb * 64 + tx];
    __syncthreads();
    for (int r = ty; r < 64; r += 4)
        PT[(size_t)(nb * 64 + r) * 256 + kb * 64 + tx] = f2b(tile[tx][r]);
}

// ---------------- cls4 = column-max of f0[:256] ----------------
__global__ void cls4_kernel(const float* __restrict__ xyzf, const float* __restrict__ Wallf,
                            const float* __restrict__ ballf, float* __restrict__ cls4) {
    __shared__ float px[256], py[256], pz[256];
    int t = threadIdx.x;
    px[t] = xyzf[3 * t + 0];
    py[t] = xyzf[3 * t + 1];
    pz[t] = xyzf[3 * t + 2];
    __syncthreads();
    float w0 = Wallf[t], w1 = Wallf[256 + t], w2 = Wallf[512 + t];
    float b = ballf[t];
    float best = -3.402823466e38f;
    for (int i = 0; i < 256; ++i) {
        float v = fmaf(pz[i], w2, fmaf(py[i], w1, px[i] * w0)) + b;
        best = fmaxf(best, v);
    }
    cls4[t] = best;
}

// ---------------- per-level folded constants (parallel version) ----------------
__global__ void prep_consts(const float* __restrict__ Pbase, const float* __restrict__ Wbase,
                            const float* __restrict__ Wallf, const float* __restrict__ ballf,
                            const float* __restrict__ cls4,
                            float* __restrict__ M1, float* __restrict__ M2,
                            float* __restrict__ cbuf) {
    int L = blockIdx.x;                    // 0 => level4 ... 4 => level0
    int tb = blockIdx.y;                   // 32-column chunk
    const float* P = Pbase + (size_t)L * 131328;
    const float* W = Wbase + (size_t)L * 1024;
    const float* b = W + 768;
    const float* pb = P + 131072;
    int tid = threadIdx.x;
    int j = tid & 31;                      // col within chunk
    int slice = tid >> 5;                  // 0..7 (32 c-values each)
    int col = tb * 32 + j;

    float m10 = 0.f, m11 = 0.f, m12 = 0.f, m20 = 0.f, m21 = 0.f, m22 = 0.f, cc = 0.f;
#pragma unroll 4
    for (int i = 0; i < 32; ++i) {
        int c = slice * 32 + i;
        float pt = P[(size_t)c * 256 + col];
        float pbot = P[(size_t)(256 + c) * 256 + col];
        m10 = fmaf(W[c], pt, m10);
        m11 = fmaf(W[256 + c], pt, m11);
        m12 = fmaf(W[512 + c], pt, m12);
        m20 = fmaf(Wallf[c], pbot, m20);
        m21 = fmaf(Wallf[256 + c], pbot, m21);
        m22 = fmaf(Wallf[512 + c], pbot, m22);
        cc = fmaf(b[c], pt, cc);
        cc = fmaf(ballf[c], pbot, cc);
        if (L == 0) cc = fmaf(cls4[c], pt, cc);
    }

    __shared__ float red[7][256];
    red[0][tid] = m10; red[1][tid] = m11; red[2][tid] = m12;
    red[3][tid] = m20; red[4][tid] = m21; red[5][tid] = m22;
    red[6][tid] = cc;
    __syncthreads();
    if (tid < 32) {
        float v[7];
#pragma unroll
        for (int q = 0; q < 7; ++q) {
            float s = red[q][tid];
#pragma unroll
            for (int sl = 1; sl < 8; ++sl) s += red[q][sl * 32 + tid];
            v[q] = s;
        }
        M1[(size_t)L * 768 + col] = v[0];
        M1[(size_t)L * 768 + 256 + col] = v[1];
        M1[(size_t)L * 768 + 512 + col] = v[2];
        M2[(size_t)L * 768 + col] = v[3];
        M2[(size_t)L * 768 + 256 + col] = v[4];
        M2[(size_t)L * 768 + 512 + col] = v[5];
        cbuf[(size_t)L * 256 + col] = v[6] + pb[col];
    }
}

// ---------------- 1-NN argmin (fp32-exact, reference op order) ----------------
__global__ void nn_kernel(const float* __restrict__ xyzf, const int* __restrict__ idxQ,
                          const int* __restrict__ idxR, int nR, int* __restrict__ outK) {
    __shared__ __align__(16) float4 ref4[1024];
    __shared__ float redD[256];
    __shared__ int redI[256];
    int tid = threadIdx.x;
    int part = tid >> 6;
    int q = blockIdx.x * 64 + (tid & 63);
    int qi = idxQ[q];
    float qx = xyzf[3 * qi + 0];
    float qy = xyzf[3 * qi + 1];
    float qz = xyzf[3 * qi + 2];
    float q2 = (qx * qx + qy * qy) + qz * qz;
    float best = 3.402823466e38f;
    int bi = 0;
    for (int base = 0; base < nR; base += 1024) {
        int nt = min(1024, nR - base);
        __syncthreads();
        for (int t = tid; t < nt; t += 256) {
            int ri = idxR[base + t];
            float x = xyzf[3 * ri + 0];
            float y = xyzf[3 * ri + 1];
            float z = xyzf[3 * ri + 2];
            ref4[t] = make_float4(x, y, z, (x * x + y * y) + z * z);
        }
        __syncthreads();
        int seg = nt >> 2;
        int s0 = part * seg;
        for (int t = 0; t < seg; ++t) {
            float4 rp = ref4[s0 + t];
            float dot = (qx * rp.x + qy * rp.y) + qz * rp.z;
            float d = (q2 - 2.0f * dot) + rp.w;
            if (d < best) { best = d; bi = base + s0 + t; }
        }
    }
    redD[tid] = best;
    redI[tid] = bi;
    __syncthreads();
    if (part == 0) {
#pragma unroll
        for (int p = 1; p < 4; ++p) {
            float d = redD[tid + p * 64];
            int i2 = redI[tid + p * 64];
            if (d < best || (d == best && i2 < bi)) { best = d; bi = i2; }
        }
        outK[q] = bi;
    }
}

// ---------------- level 4: pure rank-3 (no GEMM) ----------------
__global__ void pe4_kernel(const float* __restrict__ xyzf, const int* __restrict__ idx4,
                           const float* __restrict__ M1, const float* __restrict__ M2,
                           const float* __restrict__ cbuf, const int* __restrict__ flag,
                           void* __restrict__ outv, ushort_t* __restrict__ peB) {
    int row = blockIdx.x;
    int n = threadIdx.x;
    int qi = idx4[row];
    float qx = xyzf[3 * qi + 0], qy = xyzf[3 * qi + 1], qz = xyzf[3 * qi + 2];
    float xx = xyzf[3 * row + 0], yy = xyzf[3 * row + 1], zz = xyzf[3 * row + 2];
    float v = cbuf[n];
    v = fmaf(qx, M1[n], v);
    v = fmaf(qy, M1[256 + n], v);
    v = fmaf(qz, M1[512 + n], v);
    v = fmaf(xx, M2[n], v);
    v = fmaf(yy, M2[256 + n], v);
    v = fmaf(zz, M2[512 + n], v);
    size_t idx = (size_t)row * 256 + n;
    if (flag[0]) ((float*)outv)[idx] = v;
    else         ((bf16*)outv)[idx] = __float2bfloat16(v);
    peB[idx] = f2b(v);
}

// ---------------- MFMA level kernel (K=256, LDS-free fragment loads) ----------------
// Block: 128 rows x 256 cols, 512 threads (8 waves, each a 64x64 tile).
// A fragment (lane l16, quad): peB_prev[rowK[row]*256 + kt*32 + quad*8 ..+8]  (16B)
// B fragment (lane l16, quad): PT[col*256 + kt*32 + quad*8 ..+8]              (16B)
// Both contiguous & 16B-aligned -> direct global->VGPR, no LDS, no k-loop barriers.
__global__ __launch_bounds__(512, 4) void level_mfma(
    const float* __restrict__ xyzf,
    const ushort_t* __restrict__ peB_prev,
    const int* __restrict__ kmap,
    const int* __restrict__ idxQ,
    const int* __restrict__ idxR,
    const float* __restrict__ M1, const float* __restrict__ M2,
    const float* __restrict__ cvec,
    const ushort_t* __restrict__ PT,
    const int* __restrict__ flag, void* __restrict__ outv, size_t out_off,
    ushort_t* __restrict__ peB_out) {
    __shared__ float m1l[768], m2l[768], cl[256];
    __shared__ float rowD[128][3], rowX[128][3];
    __shared__ int rowK[128];

    int tid = threadIdx.x;
    int row0 = blockIdx.x * 128;
    int fp32out = flag[0];

    for (int i = tid; i < 768; i += 512) { m1l[i] = M1[i]; m2l[i] = M2[i]; }
    if (tid < 256) cl[tid] = cvec[tid];
    if (tid < 128) {
        int r = tid, row = row0 + r;
        float xx = xyzf[3 * row + 0];
        float yy = xyzf[3 * row + 1];
        float zz = xyzf[3 * row + 2];
        rowX[r][0] = xx; rowX[r][1] = yy; rowX[r][2] = zz;
        int k = kmap[row];
        rowK[r] = k;
        float qx = xx, qy = yy, qz = zz;
        if (idxQ) {
            int qi = idxQ[row];
            qx = xyzf[3 * qi + 0];
            qy = xyzf[3 * qi + 1];
            qz = xyzf[3 * qi + 2];
        }
        int ri = idxR[k];
        float rx = xyzf[3 * ri + 0];
        float ry = xyzf[3 * ri + 1];
        float rz = xyzf[3 * ri + 2];
        rowD[r][0] = qx - rx; rowD[r][1] = qy - ry; rowD[r][2] = qz - rz;
    }
    __syncthreads();

    int wave = tid >> 6;
    int lane = tid & 63;
    int quad = lane >> 4;
    int l16 = lane & 15;
    int wr = (wave >> 2) * 64;     // 0 / 64
    int wc = (wave & 3) * 64;      // 0 / 64 / 128 / 192

    // fragment base pointers (constant across the k-loop)
    const ushort_t* abase[4];
#pragma unroll
    for (int mt = 0; mt < 4; ++mt)
        abase[mt] = peB_prev + (size_t)rowK[wr + mt * 16 + l16] * 256 + quad * 8;
    const ushort_t* bbase[4];
#pragma unroll
    for (int nt = 0; nt < 4; ++nt)
        bbase[nt] = PT + (size_t)(wc + nt * 16 + l16) * 256 + quad * 8;

    float4v acc[4][4];
#pragma unroll
    for (int mt = 0; mt < 4; ++mt)
#pragma unroll
        for (int nt = 0; nt < 4; ++nt) acc[mt][nt] = (float4v){0.f, 0.f, 0.f, 0.f};

#pragma unroll
    for (int kt = 0; kt < 8; ++kt) {
        int c0 = kt * 32;
        short8 afr[4], bfr[4];
#pragma unroll
        for (int mt = 0; mt < 4; ++mt)
            afr[mt] = *(const short8*)(abase[mt] + c0);
#pragma unroll
        for (int nt = 0; nt < 4; ++nt)
            bfr[nt] = *(const short8*)(bbase[nt] + c0);
#pragma unroll
        for (int mt = 0; mt < 4; ++mt)
#pragma unroll
            for (int nt = 0; nt < 4; ++nt)
                acc[mt][nt] = __builtin_amdgcn_mfma_f32_16x16x32_bf16(
                    afr[mt], bfr[nt], acc[mt][nt], 0, 0, 0);
    }

    // ---- epilogue: + c + dxyz@M1 + xyz@M2 ; D row = quad*4+reg, col = lane&15 ----
#pragma unroll
    for (int mt = 0; mt < 4; ++mt) {
#pragma unroll
        for (int reg = 0; reg < 4; ++reg) {
            int rl = wr + mt * 16 + quad * 4 + reg;
            float d0 = rowD[rl][0], d1 = rowD[rl][1], d2 = rowD[rl][2];
            float x0 = rowX[rl][0], x1 = rowX[rl][1], x2 = rowX[rl][2];
            int row = row0 + rl;
#pragma unroll
            for (int nt = 0; nt < 4; ++nt) {
                int col = wc + nt * 16 + l16;
                float v = acc[mt][nt][reg] + cl[col];
                v = fmaf(d0, m1l[col], v);
                v = fmaf(d1, m1l[256 + col], v);
                v = fmaf(d2, m1l[512 + col], v);
                v = fmaf(x0, m2l[col], v);
                v = fmaf(x1, m2l[256 + col], v);
                v = fmaf(x2, m2l[512 + col], v);
                size_t idx = (size_t)row * 256 + col;
                if (fp32out) ((float*)outv)[out_off + idx] = v;
                else         ((bf16*)outv)[out_off + idx] = __float2bfloat16(v);
                if (peB_out) peB_out[idx] = f2b(v);
            }
        }
    }
}

extern "C" void kernel_launch(void* const* d_in, const int* in_sizes, int n_in,
                              void* d_out, int out_size, void* d_ws, size_t ws_size,
                              hipStream_t stream) {
    const int* idx0 = (const int*)d_in[1];
    const int* idx1 = (const int*)d_in[2];
    const int* idx2 = (const int*)d_in[3];
    const int* idx3 = (const int*)d_in[4];
    const int* idx4 = (const int*)d_in[5];

    // workspace layout (all offsets multiples of 64 floats => 16B aligned)
    float* ws = (float*)d_ws;
    int* flag = (int*)ws;            // 64 floats reserved
    float* p = ws + 64;
    float* xyzf = p;  p += 196608;
    float* Wallf = p; p += 768;
    float* ballf = p; p += 256;
    float* Wf0 = p;   p += 5 * 1024;          // (W 768 + b 256) x 5
    float* Pf0 = p;   p += 5 * 131328;        // (P 131072 + pb 256) x 5
    float* cls4 = p;  p += 256;
    float* M1buf = p; p += 5 * 768;
    float* M2buf = p; p += 5 * 768;
    float* cbuf = p;  p += 5 * 256;
    int* k34 = (int*)p; p += 1024;
    int* k23 = (int*)p; p += 4096;
    int* k12 = (int*)p; p += 16384;
    ushort_t* pe4B = (ushort_t*)p; p += 32768;     // 256*256 bf16
    ushort_t* pe3B = (ushort_t*)p; p += 131072;    // 1024*256 bf16
    ushort_t* pe2B = (ushort_t*)p; p += 524288;    // 4096*256 bf16
    ushort_t* pe1B = (ushort_t*)p; p += 2097152;   // 16384*256 bf16
    ushort_t* PTb = (ushort_t*)p;                  // 5 * 65536 bf16 (P_top^T only)

    detect_kernel<<<1, 256, 0, stream>>>((const unsigned short*)d_in[0], flag);

    CanonArgs ca;
    ca.src[0] = d_in[0];
    ca.src[1] = d_in[6];
    ca.src[2] = d_in[7];
    for (int i = 0; i < 10; ++i) ca.src[3 + i] = d_in[8 + i];
    for (int i = 0; i < 10; ++i) ca.src[13 + i] = d_in[18 + i];
    canon_kernel<<<3357, 256, 0, stream>>>(ca, flag, ws + 64);

    cls4_kernel<<<1, 256, 0, stream>>>(xyzf, Wallf, ballf, cls4);
    prep_pt<<<dim3(5, 4, 4), 256, 0, stream>>>(Pf0, PTb);
    prep_consts<<<dim3(5, 8), 256, 0, stream>>>(Pf0, Wf0, Wallf, ballf, cls4, M1buf, M2buf, cbuf);

    nn_kernel<<<cN3 / 64, 256, 0, stream>>>(xyzf, idx3, idx4, cN4, k34);
    nn_kernel<<<cN2 / 64, 256, 0, stream>>>(xyzf, idx2, idx3, cN3, k23);
    nn_kernel<<<cN1 / 64, 256, 0, stream>>>(xyzf, idx1, idx2, cN2, k12);

    const size_t o4 = 0;
    const size_t o3 = (size_t)cN4 * 256;
    const size_t o2 = o3 + (size_t)cN3 * 256;
    const size_t o1 = o2 + (size_t)cN2 * 256;
    const size_t o0 = o1 + (size_t)cN1 * 256;

    pe4_kernel<<<cN4, 256, 0, stream>>>(xyzf, idx4, M1buf, M2buf, cbuf, flag, d_out, pe4B);

    level_mfma<<<cN3 / 128, 512, 0, stream>>>(
        xyzf, pe4B, k34, idx3, idx4, M1buf + 768, M2buf + 768, cbuf + 256,
        PTb + 1 * 65536, flag, d_out, o3, pe3B);
    level_mfma<<<cN2 / 128, 512, 0, stream>>>(
        xyzf, pe3B, k23, idx2, idx3, M1buf + 2 * 768, M2buf + 2 * 768, cbuf + 2 * 256,
        PTb + 2 * 65536, flag, d_out, o2, pe2B);
    level_mfma<<<cN1 / 128, 512, 0, stream>>>(
        xyzf, pe2B, k12, idx1, idx2, M1buf + 3 * 768, M2buf + 3 * 768, cbuf + 3 * 256,
        PTb + 3 * 65536, flag, d_out, o1, pe1B);
    level_mfma<<<cN0 / 128, 512, 0, stream>>>(
        xyzf, pe1B, idx0, nullptr, idx1, M1buf + 4 * 768, M2buf + 4 * 768, cbuf + 4 * 256,
        PTb + 4 * 65536, flag, d_out, o0, nullptr);
}

// Round 4
// 290.109 us; speedup vs baseline: 1.1849x; 1.1849x over previous
//
#include <hip/hip_runtime.h>
#include <hip/hip_bf16.h>

// MultiScaleAttentionPE — MI355X round 7
// Fold kept: pe = peB[k] @ P_top (bf16 MFMA, K=256)
//               + dxyz @ (W@P_top) + xyz @ (Wall@P_bot) + c   (fp32 exact)
// Round-7: level_mfma v3 — 64-row blocks; A (64x256 bf16 = 32KB) staged in LDS
//   ONCE (1 barrier), k-loop barrier-free; B fragments direct global->VGPR
//   (each loaded exactly once per block). Prep kernels merged (prep_pt +
//   prep_consts + inline cls4); the 3 nn searches merged into one launch.

typedef __hip_bfloat16 bf16;
typedef unsigned short ushort_t;
typedef __attribute__((ext_vector_type(8))) short short8;
typedef __attribute__((ext_vector_type(4))) float float4v;

#define cN0 65536
#define cN1 16384
#define cN2 4096
#define cN3 1024
#define cN4 256

__device__ __forceinline__ float b2f(bf16 v) { return __bfloat162float(v); }

// RNE float -> bf16 bits (values are finite; no NaN path needed)
__device__ __forceinline__ ushort_t f2b(float v) {
    union { float f; unsigned u; } x; x.f = v;
    unsigned r = x.u + 0x7FFF + ((x.u >> 16) & 1);
    return (ushort_t)(r >> 16);
}

// ---------------- dtype detect (bf16 vs fp32 storage) ----------------
__global__ void detect_kernel(const unsigned short* __restrict__ raw, int* __restrict__ flag) {
    __shared__ int bad;
    if (threadIdx.x == 0) bad = 0;
    __syncthreads();
    for (int i = threadIdx.x; i < 1024; i += 256) {
        int e = (raw[i] >> 7) & 0xFF;
        if (e >= 138) atomicOr(&bad, 1);
    }
    __syncthreads();
    if (threadIdx.x == 0) flag[0] = bad ? 1 : 0;
}

// ---------------- canonicalize all float tensors to fp32 ----------------
struct CanonArgs { const void* src[23]; };

__global__ void canon_kernel(CanonArgs a, const int* __restrict__ flag, float* __restrict__ dst) {
    const int sizes[23] = {196608, 768, 256,
                           768, 256, 768, 256, 768, 256, 768, 256, 768, 256,
                           131072, 256, 131072, 256, 131072, 256, 131072, 256, 131072, 256};
    int fp32 = flag[0];
    int gid = blockIdx.x * 256 + threadIdx.x;
    int off = 0;
#pragma unroll
    for (int s = 0; s < 23; ++s) {
        int n = sizes[s];
        if (gid >= off && gid < off + n) {
            int local = gid - off;
            float v = fp32 ? ((const float*)a.src[s])[local]
                           : b2f(((const bf16*)a.src[s])[local]);
            dst[gid] = v;
        }
        off += n;
    }
}

// ---------------- merged prep: P^T transpose + folded consts (+inline cls4) ----------------
// blocks 0..79  : P_top -> P_top^T bf16   (level = b>>4, kb = (b>>2)&3, nb = b&3)
// blocks 80..119: M1/M2/c fold            (L = (b-80)>>3, tb = (b-80)&7)
//                 L==0 blocks compute cls4 inline from xyz[:256].
__global__ void prep_kernel(const float* __restrict__ Pbase, const float* __restrict__ Wbase,
                            const float* __restrict__ Wallf, const float* __restrict__ ballf,
                            const float* __restrict__ xyzf,
                            ushort_t* __restrict__ PTb,
                            float* __restrict__ M1, float* __restrict__ M2,
                            float* __restrict__ cbuf) {
    __shared__ __align__(16) char smem[16640];
    int bidx = blockIdx.x;
    int tid = threadIdx.x;

    if (bidx < 80) {
        // ---- transpose path (identical arithmetic to round-5 prep_pt) ----
        int level = bidx >> 4;
        int kb = (bidx >> 2) & 3;
        int nb = bidx & 3;
        const float* P = Pbase + (size_t)level * 131328;
        ushort_t* PT = PTb + (size_t)level * 65536;
        float (*tile)[65] = (float (*)[65])smem;
        int tx = tid & 63, ty = tid >> 6;
        for (int r = ty; r < 64; r += 4)
            tile[r][tx] = P[(size_t)(kb * 64 + r) * 256 + nb * 64 + tx];
        __syncthreads();
        for (int r = ty; r < 64; r += 4)
            PT[(size_t)(nb * 64 + r) * 256 + kb * 64 + tx] = f2b(tile[tx][r]);
        return;
    }

    // ---- consts path ----
    int L = (bidx - 80) >> 3;
    int tb = (bidx - 80) & 7;
    const float* P = Pbase + (size_t)L * 131328;
    const float* W = Wbase + (size_t)L * 1024;
    const float* b = W + 768;
    const float* pb = P + 131072;

    float* cls4f = (float*)smem;                 // 256 floats
    float* red = (float*)(smem + 1024);          // 7*256 floats
    float* px = (float*)(smem + 1024 + 7168);    // 256
    float* py = px + 256;
    float* pz = py + 256;

    if (L == 0) {
        // inline cls4: max over 256 rows of xyz[:256]@Wall + ball (exact op order
        // of the former cls4_kernel)
        px[tid] = xyzf[3 * tid + 0];
        py[tid] = xyzf[3 * tid + 1];
        pz[tid] = xyzf[3 * tid + 2];
        __syncthreads();
        float w0 = Wallf[tid], w1 = Wallf[256 + tid], w2 = Wallf[512 + tid];
        float bb = ballf[tid];
        float best = -3.402823466e38f;
        for (int i = 0; i < 256; ++i) {
            float v = fmaf(pz[i], w2, fmaf(py[i], w1, px[i] * w0)) + bb;
            best = fmaxf(best, v);
        }
        cls4f[tid] = best;
        __syncthreads();
    }

    int j = tid & 31;
    int slice = tid >> 5;
    int col = tb * 32 + j;

    float m10 = 0.f, m11 = 0.f, m12 = 0.f, m20 = 0.f, m21 = 0.f, m22 = 0.f, cc = 0.f;
#pragma unroll 4
    for (int i = 0; i < 32; ++i) {
        int c = slice * 32 + i;
        float pt = P[(size_t)c * 256 + col];
        float pbot = P[(size_t)(256 + c) * 256 + col];
        m10 = fmaf(W[c], pt, m10);
        m11 = fmaf(W[256 + c], pt, m11);
        m12 = fmaf(W[512 + c], pt, m12);
        m20 = fmaf(Wallf[c], pbot, m20);
        m21 = fmaf(Wallf[256 + c], pbot, m21);
        m22 = fmaf(Wallf[512 + c], pbot, m22);
        cc = fmaf(b[c], pt, cc);
        cc = fmaf(ballf[c], pbot, cc);
        if (L == 0) cc = fmaf(cls4f[c], pt, cc);
    }

    red[0 * 256 + tid] = m10; red[1 * 256 + tid] = m11; red[2 * 256 + tid] = m12;
    red[3 * 256 + tid] = m20; red[4 * 256 + tid] = m21; red[5 * 256 + tid] = m22;
    red[6 * 256 + tid] = cc;
    __syncthreads();
    if (tid < 32) {
        float v[7];
#pragma unroll
        for (int q = 0; q < 7; ++q) {
            float s = red[q * 256 + tid];
#pragma unroll
            for (int sl = 1; sl < 8; ++sl) s += red[q * 256 + sl * 32 + tid];
            v[q] = s;
        }
        M1[(size_t)L * 768 + col] = v[0];
        M1[(size_t)L * 768 + 256 + col] = v[1];
        M1[(size_t)L * 768 + 512 + col] = v[2];
        M2[(size_t)L * 768 + col] = v[3];
        M2[(size_t)L * 768 + 256 + col] = v[4];
        M2[(size_t)L * 768 + 512 + col] = v[5];
        cbuf[(size_t)L * 256 + col] = v[6] + pb[col];
    }
}

// ---------------- merged 1-NN argmin (3 levels, one launch) ----------------
__device__ __forceinline__ void nn_body(const float* __restrict__ xyzf,
                                        const int* __restrict__ idxQ,
                                        const int* __restrict__ idxR, int nR,
                                        int* __restrict__ outK, int blk,
                                        float4* ref4, float* redD, int* redI) {
    int tid = threadIdx.x;
    int part = tid >> 6;
    int q = blk * 64 + (tid & 63);
    int qi = idxQ[q];
    float qx = xyzf[3 * qi + 0];
    float qy = xyzf[3 * qi + 1];
    float qz = xyzf[3 * qi + 2];
    float q2 = (qx * qx + qy * qy) + qz * qz;
    float best = 3.402823466e38f;
    int bi = 0;
    for (int base = 0; base < nR; base += 1024) {
        int nt = min(1024, nR - base);
        __syncthreads();
        for (int t = tid; t < nt; t += 256) {
            int ri = idxR[base + t];
            float x = xyzf[3 * ri + 0];
            float y = xyzf[3 * ri + 1];
            float z = xyzf[3 * ri + 2];
            ref4[t] = make_float4(x, y, z, (x * x + y * y) + z * z);
        }
        __syncthreads();
        int seg = nt >> 2;
        int s0 = part * seg;
        for (int t = 0; t < seg; ++t) {
            float4 rp = ref4[s0 + t];
            float dot = (qx * rp.x + qy * rp.y) + qz * rp.z;
            float d = (q2 - 2.0f * dot) + rp.w;
            if (d < best) { best = d; bi = base + s0 + t; }
        }
    }
    redD[tid] = best;
    redI[tid] = bi;
    __syncthreads();
    if (part == 0) {
#pragma unroll
        for (int p = 1; p < 4; ++p) {
            float d = redD[tid + p * 64];
            int i2 = redI[tid + p * 64];
            if (d < best || (d == best && i2 < bi)) { best = d; bi = i2; }
        }
        outK[q] = bi;
    }
}

__global__ void nn_merged(const float* __restrict__ xyzf,
                          const int* __restrict__ idx1, const int* __restrict__ idx2,
                          const int* __restrict__ idx3, const int* __restrict__ idx4,
                          int* __restrict__ k34, int* __restrict__ k23,
                          int* __restrict__ k12) {
    __shared__ __align__(16) float4 ref4[1024];
    __shared__ float redD[256];
    __shared__ int redI[256];
    int b = blockIdx.x;
    if (b < 16)       nn_body(xyzf, idx3, idx4, cN4, k34, b, ref4, redD, redI);
    else if (b < 80)  nn_body(xyzf, idx2, idx3, cN3, k23, b - 16, ref4, redD, redI);
    else              nn_body(xyzf, idx1, idx2, cN2, k12, b - 80, ref4, redD, redI);
}

// ---------------- level 4: pure rank-3 (no GEMM) ----------------
__global__ void pe4_kernel(const float* __restrict__ xyzf, const int* __restrict__ idx4,
                           const float* __restrict__ M1, const float* __restrict__ M2,
                           const float* __restrict__ cbuf, const int* __restrict__ flag,
                           void* __restrict__ outv, ushort_t* __restrict__ peB) {
    int row = blockIdx.x;
    int n = threadIdx.x;
    int qi = idx4[row];
    float qx = xyzf[3 * qi + 0], qy = xyzf[3 * qi + 1], qz = xyzf[3 * qi + 2];
    float xx = xyzf[3 * row + 0], yy = xyzf[3 * row + 1], zz = xyzf[3 * row + 2];
    float v = cbuf[n];
    v = fmaf(qx, M1[n], v);
    v = fmaf(qy, M1[256 + n], v);
    v = fmaf(qz, M1[512 + n], v);
    v = fmaf(xx, M2[n], v);
    v = fmaf(yy, M2[256 + n], v);
    v = fmaf(zz, M2[512 + n], v);
    size_t idx = (size_t)row * 256 + n;
    if (flag[0]) ((float*)outv)[idx] = v;
    else         ((bf16*)outv)[idx] = __float2bfloat16(v);
    peB[idx] = f2b(v);
}

// ---------------- MFMA level kernel v3 ----------------
// Block: 64 rows x 256 cols, 256 threads (4 waves, each 64x64).
// A (64 rows x K=256 bf16, gathered rows) staged in LDS ONCE -> 1 barrier,
// then fully-unrolled k-loop with no barriers. B fragments (contiguous 16B in
// PT) loaded direct global->VGPR, exactly once per block.
__global__ __launch_bounds__(256, 2) void level_mfma(
    const float* __restrict__ xyzf,
    const ushort_t* __restrict__ peB_prev,
    const int* __restrict__ kmap,
    const int* __restrict__ idxQ,
    const int* __restrict__ idxR,
    const float* __restrict__ M1, const float* __restrict__ M2,
    const float* __restrict__ cvec,
    const ushort_t* __restrict__ PT,
    const int* __restrict__ flag, void* __restrict__ outv, size_t out_off,
    ushort_t* __restrict__ peB_out) {
    __shared__ float m1l[768], m2l[768], cl[256];
    __shared__ float rowD[64][3], rowX[64][3];
    __shared__ int rowK[64];
    __shared__ __align__(16) ushort_t A_lds[64 * 264];   // stride 264 (+8 pad)

    int tid = threadIdx.x;
    int row0 = blockIdx.x * 64;
    int fp32out = flag[0];

    for (int i = tid; i < 768; i += 256) { m1l[i] = M1[i]; m2l[i] = M2[i]; }
    cl[tid] = cvec[tid];
    if (tid < 64) {
        int r = tid, row = row0 + r;
        float xx = xyzf[3 * row + 0];
        float yy = xyzf[3 * row + 1];
        float zz = xyzf[3 * row + 2];
        rowX[r][0] = xx; rowX[r][1] = yy; rowX[r][2] = zz;
        int k = kmap[row];
        rowK[r] = k;
        float qx = xx, qy = yy, qz = zz;
        if (idxQ) {
            int qi = idxQ[row];
            qx = xyzf[3 * qi + 0];
            qy = xyzf[3 * qi + 1];
            qz = xyzf[3 * qi + 2];
        }
        int ri = idxR[k];
        float rx = xyzf[3 * ri + 0];
        float ry = xyzf[3 * ri + 1];
        float rz = xyzf[3 * ri + 2];
        rowD[r][0] = qx - rx; rowD[r][1] = qy - ry; rowD[r][2] = qz - rz;
    }
    __syncthreads();

    // ---- stage A once: 64 rows x 256 k (32 chunks of 16B per row) ----
#pragma unroll
    for (int it = 0; it < 8; ++it) {
        int lin = it * 256 + tid;          // 0..2047
        int r = lin >> 5, ch = lin & 31;
        *(uint4*)&A_lds[r * 264 + ch * 8] =
            *(const uint4*)(peB_prev + (size_t)rowK[r] * 256 + ch * 8);
    }
    __syncthreads();

    int wave = tid >> 6;
    int lane = tid & 63;
    int quad = lane >> 4;
    int l16 = lane & 15;
    int wc = wave * 64;

    const ushort_t* bbase[4];
#pragma unroll
    for (int nt = 0; nt < 4; ++nt)
        bbase[nt] = PT + (size_t)(wc + nt * 16 + l16) * 256 + quad * 8;

    float4v acc[4][4];
#pragma unroll
    for (int mt = 0; mt < 4; ++mt)
#pragma unroll
        for (int nt = 0; nt < 4; ++nt) acc[mt][nt] = (float4v){0.f, 0.f, 0.f, 0.f};

#pragma unroll
    for (int kt = 0; kt < 8; ++kt) {
        int c0 = kt * 32;
        short8 afr[4], bfr[4];
#pragma unroll
        for (int nt = 0; nt < 4; ++nt)
            bfr[nt] = *(const short8*)(bbase[nt] + c0);
#pragma unroll
        for (int mt = 0; mt < 4; ++mt)
            afr[mt] = *(const short8*)&A_lds[(mt * 16 + l16) * 264 + c0 + quad * 8];
#pragma unroll
        for (int mt = 0; mt < 4; ++mt)
#pragma unroll
            for (int nt = 0; nt < 4; ++nt)
                acc[mt][nt] = __builtin_amdgcn_mfma_f32_16x16x32_bf16(
                    afr[mt], bfr[nt], acc[mt][nt], 0, 0, 0);
    }

    // ---- epilogue: + c + dxyz@M1 + xyz@M2 ; D row = quad*4+reg, col = lane&15 ----
#pragma unroll
    for (int mt = 0; mt < 4; ++mt) {
#pragma unroll
        for (int reg = 0; reg < 4; ++reg) {
            int rl = mt * 16 + quad * 4 + reg;
            float d0 = rowD[rl][0], d1 = rowD[rl][1], d2 = rowD[rl][2];
            float x0 = rowX[rl][0], x1 = rowX[rl][1], x2 = rowX[rl][2];
            int row = row0 + rl;
#pragma unroll
            for (int nt = 0; nt < 4; ++nt) {
                int col = wc + nt * 16 + l16;
                float v = acc[mt][nt][reg] + cl[col];
                v = fmaf(d0, m1l[col], v);
                v = fmaf(d1, m1l[256 + col], v);
                v = fmaf(d2, m1l[512 + col], v);
                v = fmaf(x0, m2l[col], v);
                v = fmaf(x1, m2l[256 + col], v);
                v = fmaf(x2, m2l[512 + col], v);
                size_t idx = (size_t)row * 256 + col;
                if (fp32out) ((float*)outv)[out_off + idx] = v;
                else         ((bf16*)outv)[out_off + idx] = __float2bfloat16(v);
                if (peB_out) peB_out[idx] = f2b(v);
            }
        }
    }
}

extern "C" void kernel_launch(void* const* d_in, const int* in_sizes, int n_in,
                              void* d_out, int out_size, void* d_ws, size_t ws_size,
                              hipStream_t stream) {
    const int* idx0 = (const int*)d_in[1];
    const int* idx1 = (const int*)d_in[2];
    const int* idx2 = (const int*)d_in[3];
    const int* idx3 = (const int*)d_in[4];
    const int* idx4 = (const int*)d_in[5];

    // workspace layout (all offsets multiples of 64 floats => 16B aligned)
    float* ws = (float*)d_ws;
    int* flag = (int*)ws;            // 64 floats reserved
    float* p = ws + 64;
    float* xyzf = p;  p += 196608;
    float* Wallf = p; p += 768;
    float* ballf = p; p += 256;
    float* Wf0 = p;   p += 5 * 1024;          // (W 768 + b 256) x 5
    float* Pf0 = p;   p += 5 * 131328;        // (P 131072 + pb 256) x 5
    float* M1buf = p; p += 5 * 768;
    float* M2buf = p; p += 5 * 768;
    float* cbuf = p;  p += 5 * 256;
    int* k34 = (int*)p; p += 1024;
    int* k23 = (int*)p; p += 4096;
    int* k12 = (int*)p; p += 16384;
    ushort_t* pe4B = (ushort_t*)p; p += 32768;     // 256*256 bf16
    ushort_t* pe3B = (ushort_t*)p; p += 131072;    // 1024*256 bf16
    ushort_t* pe2B = (ushort_t*)p; p += 524288;    // 4096*256 bf16
    ushort_t* pe1B = (ushort_t*)p; p += 2097152;   // 16384*256 bf16
    ushort_t* PTb = (ushort_t*)p;                  // 5 * 65536 bf16 (P_top^T only)

    detect_kernel<<<1, 256, 0, stream>>>((const unsigned short*)d_in[0], flag);

    CanonArgs ca;
    ca.src[0] = d_in[0];
    ca.src[1] = d_in[6];
    ca.src[2] = d_in[7];
    for (int i = 0; i < 10; ++i) ca.src[3 + i] = d_in[8 + i];
    for (int i = 0; i < 10; ++i) ca.src[13 + i] = d_in[18 + i];
    canon_kernel<<<3357, 256, 0, stream>>>(ca, flag, ws + 64);

    prep_kernel<<<120, 256, 0, stream>>>(Pf0, Wf0, Wallf, ballf, xyzf,
                                         PTb, M1buf, M2buf, cbuf);
    nn_merged<<<336, 256, 0, stream>>>(xyzf, idx1, idx2, idx3, idx4, k34, k23, k12);

    const size_t o4 = 0;
    const size_t o3 = (size_t)cN4 * 256;
    const size_t o2 = o3 + (size_t)cN3 * 256;
    const size_t o1 = o2 + (size_t)cN2 * 256;
    const size_t o0 = o1 + (size_t)cN1 * 256;

    pe4_kernel<<<cN4, 256, 0, stream>>>(xyzf, idx4, M1buf, M2buf, cbuf, flag, d_out, pe4B);

    level_mfma<<<cN3 / 64, 256, 0, stream>>>(
        xyzf, pe4B, k34, idx3, idx4, M1buf + 768, M2buf + 768, cbuf + 256,
        PTb + 1 * 65536, flag, d_out, o3, pe3B);
    level_mfma<<<cN2 / 64, 256, 0, stream>>>(
        xyzf, pe3B, k23, idx2, idx3, M1buf + 2 * 768, M2buf + 2 * 768, cbuf + 2 * 256,
        PTb + 2 * 65536, flag, d_out, o2, pe2B);
    level_mfma<<<cN1 / 64, 256, 0, stream>>>(
        xyzf, pe2B, k12, idx1, idx2, M1buf + 3 * 768, M2buf + 3 * 768, cbuf + 3 * 256,
        PTb + 3 * 65536, flag, d_out, o1, pe1B);
    level_mfma<<<cN0 / 64, 256, 0, stream>>>(
        xyzf, pe1B, idx0, nullptr, idx1, M1buf + 4 * 768, M2buf + 4 * 768, cbuf + 4 * 256,
        PTb + 4 * 65536, flag, d_out, o0, nullptr);
}

// Round 5
// 254.362 us; speedup vs baseline: 1.3514x; 1.1405x over previous
//
#include <hip/hip_runtime.h>
#include <hip/hip_bf16.h>

// MultiScaleAttentionPE — MI355X round 8
// Fold kept: pe = peB[k] @ P_top (bf16 MFMA, K=256)
//               + dxyz @ (W@P_top) + xyz @ (Wall@P_bot) + c   (fp32 exact)
// Round-8: dispatch graph 9 -> 6.
//   - detect folded into canon (per-block recompute, block 0 publishes flag)
//   - prep (transpose+consts+cls4) and all 3 nn searches merged into ONE launch
//   - pe4_kernel deleted: L3 builds its A-rows from the rank-6 affine form
//     (bit-identical fmaf chain + f2b), 4 extra L3 blocks write the pe4 output.

typedef __hip_bfloat16 bf16;
typedef unsigned short ushort_t;
typedef __attribute__((ext_vector_type(8))) short short8;
typedef __attribute__((ext_vector_type(4))) float float4v;

#define cN0 65536
#define cN1 16384
#define cN2 4096
#define cN3 1024
#define cN4 256

__device__ __forceinline__ float b2f(bf16 v) { return __bfloat162float(v); }

// RNE float -> bf16 bits (values are finite; no NaN path needed)
__device__ __forceinline__ ushort_t f2b(float v) {
    union { float f; unsigned u; } x; x.f = v;
    unsigned r = x.u + 0x7FFF + ((x.u >> 16) & 1);
    return (ushort_t)(r >> 16);
}

// ---------------- canonicalize (with inline dtype detect) ----------------
struct CanonArgs { const void* src[23]; };

__global__ void canon_kernel(CanonArgs a, int* __restrict__ flag, float* __restrict__ dst) {
    __shared__ int bad;
    int tid = threadIdx.x;
    if (tid == 0) bad = 0;
    __syncthreads();
    const unsigned short* raw = (const unsigned short*)a.src[0];
    for (int i = tid; i < 1024; i += 256) {
        int e = (raw[i] >> 7) & 0xFF;
        if (e >= 138) atomicOr(&bad, 1);
    }
    __syncthreads();
    int fp32 = bad ? 1 : 0;
    int gid = blockIdx.x * 256 + tid;
    if (gid == 0) flag[0] = fp32;

    const int sizes[23] = {196608, 768, 256,
                           768, 256, 768, 256, 768, 256, 768, 256, 768, 256,
                           131072, 256, 131072, 256, 131072, 256, 131072, 256, 131072, 256};
    int off = 0;
#pragma unroll
    for (int s = 0; s < 23; ++s) {
        int n = sizes[s];
        if (gid >= off && gid < off + n) {
            int local = gid - off;
            float v = fp32 ? ((const float*)a.src[s])[local]
                           : b2f(((const bf16*)a.src[s])[local]);
            dst[gid] = v;
        }
        off += n;
    }
}

// ---------------- merged prep + nn (one launch, 512 threads) ----------------
// blocks   0..79 : P_top -> P_top^T bf16  (level=b>>4, kb=(b>>2)&3, nb=b&3)
// blocks  80..119: M1/M2/c fold (L=(b-80)>>3, tb=(b-80)&7); L==0 inlines cls4
// blocks 120..455: 1-NN argmin (16 blk k34, 64 blk k23, 256 blk k12)

__device__ __forceinline__ void nn_body(const float* __restrict__ xyzf,
                                        const int* __restrict__ idxQ,
                                        const int* __restrict__ idxR, int nR,
                                        int* __restrict__ outK, int blk,
                                        float4* ref4, float* redD, int* redI) {
    int tid = threadIdx.x;
    int part = tid >> 6;                   // 0..7
    int q = blk * 64 + (tid & 63);
    int qi = idxQ[q];
    float qx = xyzf[3 * qi + 0];
    float qy = xyzf[3 * qi + 1];
    float qz = xyzf[3 * qi + 2];
    float q2 = (qx * qx + qy * qy) + qz * qz;
    float best = 3.402823466e38f;
    int bi = 0;
    for (int base = 0; base < nR; base += 1024) {
        int nt = min(1024, nR - base);
        __syncthreads();
        for (int t = tid; t < nt; t += 512) {
            int ri = idxR[base + t];
            float x = xyzf[3 * ri + 0];
            float y = xyzf[3 * ri + 1];
            float z = xyzf[3 * ri + 2];
            ref4[t] = make_float4(x, y, z, (x * x + y * y) + z * z);
        }
        __syncthreads();
        int seg = nt >> 3;
        int s0 = part * seg;
        for (int t = 0; t < seg; ++t) {
            float4 rp = ref4[s0 + t];
            float dot = (qx * rp.x + qy * rp.y) + qz * rp.z;
            float d = (q2 - 2.0f * dot) + rp.w;
            if (d < best) { best = d; bi = base + s0 + t; }
        }
    }
    redD[tid] = best;
    redI[tid] = bi;
    __syncthreads();
    if (part == 0) {
#pragma unroll
        for (int p = 1; p < 8; ++p) {
            float d = redD[tid + p * 64];
            int i2 = redI[tid + p * 64];
            if (d < best || (d == best && i2 < bi)) { best = d; bi = i2; }
        }
        outK[q] = bi;
    }
}

__global__ void prep_nn_kernel(const float* __restrict__ Pbase, const float* __restrict__ Wbase,
                               const float* __restrict__ Wallf, const float* __restrict__ ballf,
                               const float* __restrict__ xyzf,
                               const int* __restrict__ idx1, const int* __restrict__ idx2,
                               const int* __restrict__ idx3, const int* __restrict__ idx4,
                               ushort_t* __restrict__ PTb,
                               float* __restrict__ M1, float* __restrict__ M2,
                               float* __restrict__ cbuf,
                               int* __restrict__ k34, int* __restrict__ k23,
                               int* __restrict__ k12) {
    __shared__ __align__(16) char smem[20608];
    int b = blockIdx.x;
    int tid = threadIdx.x;

    if (b < 80) {
        // ---- transpose path (arithmetic identical to round-7) ----
        int level = b >> 4;
        int kb = (b >> 2) & 3;
        int nb = b & 3;
        const float* P = Pbase + (size_t)level * 131328;
        ushort_t* PT = PTb + (size_t)level * 65536;
        float (*tile)[65] = (float (*)[65])smem;
        int tx = tid & 63, ty = tid >> 6;          // ty 0..7
        for (int r = ty; r < 64; r += 8)
            tile[r][tx] = P[(size_t)(kb * 64 + r) * 256 + nb * 64 + tx];
        __syncthreads();
        for (int r = ty; r < 64; r += 8)
            PT[(size_t)(nb * 64 + r) * 256 + kb * 64 + tx] = f2b(tile[tx][r]);
        return;
    }

    if (b < 120) {
        // ---- consts path ----
        int L = (b - 80) >> 3;
        int tb = (b - 80) & 7;
        const float* P = Pbase + (size_t)L * 131328;
        const float* W = Wbase + (size_t)L * 1024;
        const float* bvec = W + 768;
        const float* pb = P + 131072;
        float* cls4f = (float*)smem;                 // 256
        float* red = (float*)(smem + 1024);          // 7*256
        float* px = (float*)(smem + 1024 + 7168);
        float* py = px + 256;
        float* pz = py + 256;

        if (L == 0) {
            if (tid < 256) {
                px[tid] = xyzf[3 * tid + 0];
                py[tid] = xyzf[3 * tid + 1];
                pz[tid] = xyzf[3 * tid + 2];
            }
            __syncthreads();
            if (tid < 256) {
                float w0 = Wallf[tid], w1 = Wallf[256 + tid], w2 = Wallf[512 + tid];
                float bb = ballf[tid];
                float best = -3.402823466e38f;
                for (int i = 0; i < 256; ++i) {
                    float v = fmaf(pz[i], w2, fmaf(py[i], w1, px[i] * w0)) + bb;
                    best = fmaxf(best, v);
                }
                cls4f[tid] = best;
            }
            __syncthreads();
        }

        if (tid < 256) {
            int j = tid & 31;
            int slice = tid >> 5;
            int col = tb * 32 + j;
            float m10 = 0.f, m11 = 0.f, m12 = 0.f, m20 = 0.f, m21 = 0.f, m22 = 0.f, cc = 0.f;
#pragma unroll 4
            for (int i = 0; i < 32; ++i) {
                int c = slice * 32 + i;
                float pt = P[(size_t)c * 256 + col];
                float pbot = P[(size_t)(256 + c) * 256 + col];
                m10 = fmaf(W[c], pt, m10);
                m11 = fmaf(W[256 + c], pt, m11);
                m12 = fmaf(W[512 + c], pt, m12);
                m20 = fmaf(Wallf[c], pbot, m20);
                m21 = fmaf(Wallf[256 + c], pbot, m21);
                m22 = fmaf(Wallf[512 + c], pbot, m22);
                cc = fmaf(bvec[c], pt, cc);
                cc = fmaf(ballf[c], pbot, cc);
                if (L == 0) cc = fmaf(cls4f[c], pt, cc);
            }
            red[0 * 256 + tid] = m10; red[1 * 256 + tid] = m11; red[2 * 256 + tid] = m12;
            red[3 * 256 + tid] = m20; red[4 * 256 + tid] = m21; red[5 * 256 + tid] = m22;
            red[6 * 256 + tid] = cc;
        }
        __syncthreads();
        if (tid < 32) {
            int col = tb * 32 + tid;
            float v[7];
#pragma unroll
            for (int q = 0; q < 7; ++q) {
                float s = red[q * 256 + tid];
#pragma unroll
                for (int sl = 1; sl < 8; ++sl) s += red[q * 256 + sl * 32 + tid];
                v[q] = s;
            }
            M1[(size_t)L * 768 + col] = v[0];
            M1[(size_t)L * 768 + 256 + col] = v[1];
            M1[(size_t)L * 768 + 512 + col] = v[2];
            M2[(size_t)L * 768 + col] = v[3];
            M2[(size_t)L * 768 + 256 + col] = v[4];
            M2[(size_t)L * 768 + 512 + col] = v[5];
            cbuf[(size_t)L * 256 + col] = v[6] + pb[col];
        }
        return;
    }

    // ---- nn path ----
    int blk = b - 120;
    float4* ref4 = (float4*)smem;              // 1024 * 16B
    float* redD = (float*)(smem + 16384);      // 512
    int* redI = (int*)(smem + 18432);          // 512
    if (blk < 16)       nn_body(xyzf, idx3, idx4, cN4, k34, blk, ref4, redD, redI);
    else if (blk < 80)  nn_body(xyzf, idx2, idx3, cN3, k23, blk - 16, ref4, redD, redI);
    else                nn_body(xyzf, idx1, idx2, cN2, k12, blk - 80, ref4, redD, redI);
}

// ---------------- level 3 kernel: inline pe4 A-build + pe4 output blocks ----------------
// blocks 0..15 : 64-row L3 MFMA tiles; A rows computed from the rank-6 affine
//                pe4 form (bit-identical fmaf chain + f2b), staged once in LDS.
// blocks 16..19: write pe4 output region (64 rows each).
__global__ __launch_bounds__(256, 2) void level3_kernel(
    const float* __restrict__ xyzf,
    const int* __restrict__ idx3, const int* __restrict__ idx4,
    const int* __restrict__ k34,
    const float* __restrict__ M1_0, const float* __restrict__ M2_0,
    const float* __restrict__ c0,
    const float* __restrict__ M1_1, const float* __restrict__ M2_1,
    const float* __restrict__ c1,
    const ushort_t* __restrict__ PT,
    const int* __restrict__ flag, void* __restrict__ outv,
    size_t o4, size_t o3, ushort_t* __restrict__ peB_out) {
    __shared__ float m1l[768], m2l[768], cl[256];
    __shared__ float rowD[64][3], rowX[64][3], refQ[64][3], refK[64][3];
    __shared__ int rowK[64];
    __shared__ __align__(16) ushort_t A_lds[64 * 264];

    int tid = threadIdx.x;
    int b = blockIdx.x;
    int fp32out = flag[0];

    if (b >= 16) {
        // ---- pe4 output blocks (exact pe4_kernel fmaf chain) ----
        int rows0 = (b - 16) * 64;
        if (tid < 64) {
            int k = rows0 + tid;
            int qi = idx4[k];
            refQ[tid][0] = xyzf[3 * qi + 0];
            refQ[tid][1] = xyzf[3 * qi + 1];
            refQ[tid][2] = xyzf[3 * qi + 2];
            refK[tid][0] = xyzf[3 * k + 0];
            refK[tid][1] = xyzf[3 * k + 1];
            refK[tid][2] = xyzf[3 * k + 2];
        }
        __syncthreads();
        float cc = c0[tid];
        float a0 = M1_0[tid], a1 = M1_0[256 + tid], a2 = M1_0[512 + tid];
        float b0 = M2_0[tid], b1 = M2_0[256 + tid], b2 = M2_0[512 + tid];
        for (int r = 0; r < 64; ++r) {
            float v = cc;
            v = fmaf(refQ[r][0], a0, v);
            v = fmaf(refQ[r][1], a1, v);
            v = fmaf(refQ[r][2], a2, v);
            v = fmaf(refK[r][0], b0, v);
            v = fmaf(refK[r][1], b1, v);
            v = fmaf(refK[r][2], b2, v);
            size_t idx = o4 + (size_t)(rows0 + r) * 256 + tid;
            if (fp32out) ((float*)outv)[idx] = v;
            else         ((bf16*)outv)[idx] = __float2bfloat16(v);
        }
        return;
    }

    // ---- L3 MFMA tile ----
    int row0 = b * 64;
    for (int i = tid; i < 768; i += 256) { m1l[i] = M1_1[i]; m2l[i] = M2_1[i]; }
    cl[tid] = c1[tid];
    if (tid < 64) {
        int r = tid, row = row0 + r;
        float xx = xyzf[3 * row + 0];
        float yy = xyzf[3 * row + 1];
        float zz = xyzf[3 * row + 2];
        rowX[r][0] = xx; rowX[r][1] = yy; rowX[r][2] = zz;
        int k = k34[row];
        rowK[r] = k;
        int qi = idx3[row];
        float qx = xyzf[3 * qi + 0];
        float qy = xyzf[3 * qi + 1];
        float qz = xyzf[3 * qi + 2];
        int ri = idx4[k];
        float rx = xyzf[3 * ri + 0];
        float ry = xyzf[3 * ri + 1];
        float rz = xyzf[3 * ri + 2];
        rowD[r][0] = qx - rx; rowD[r][1] = qy - ry; rowD[r][2] = qz - rz;
        refQ[r][0] = rx; refQ[r][1] = ry; refQ[r][2] = rz;        // pe4 q-coords == ref
        refK[r][0] = xyzf[3 * k + 0];
        refK[r][1] = xyzf[3 * k + 1];
        refK[r][2] = xyzf[3 * k + 2];
    }
    __syncthreads();

    // ---- build A rows = pe4[rowK[r]] via rank-6 affine (bit-identical) ----
    {
        float cc = c0[tid];
        float a0 = M1_0[tid], a1 = M1_0[256 + tid], a2 = M1_0[512 + tid];
        float b0 = M2_0[tid], b1 = M2_0[256 + tid], b2 = M2_0[512 + tid];
        for (int r = 0; r < 64; ++r) {
            float v = cc;
            v = fmaf(refQ[r][0], a0, v);
            v = fmaf(refQ[r][1], a1, v);
            v = fmaf(refQ[r][2], a2, v);
            v = fmaf(refK[r][0], b0, v);
            v = fmaf(refK[r][1], b1, v);
            v = fmaf(refK[r][2], b2, v);
            A_lds[r * 264 + tid] = f2b(v);
        }
    }
    __syncthreads();

    int wave = tid >> 6;
    int lane = tid & 63;
    int quad = lane >> 4;
    int l16 = lane & 15;
    int wc = wave * 64;

    const ushort_t* bbase[4];
#pragma unroll
    for (int nt = 0; nt < 4; ++nt)
        bbase[nt] = PT + (size_t)(wc + nt * 16 + l16) * 256 + quad * 8;

    float4v acc[4][4];
#pragma unroll
    for (int mt = 0; mt < 4; ++mt)
#pragma unroll
        for (int nt = 0; nt < 4; ++nt) acc[mt][nt] = (float4v){0.f, 0.f, 0.f, 0.f};

#pragma unroll
    for (int kt = 0; kt < 8; ++kt) {
        int c0k = kt * 32;
        short8 afr[4], bfr[4];
#pragma unroll
        for (int nt = 0; nt < 4; ++nt)
            bfr[nt] = *(const short8*)(bbase[nt] + c0k);
#pragma unroll
        for (int mt = 0; mt < 4; ++mt)
            afr[mt] = *(const short8*)&A_lds[(mt * 16 + l16) * 264 + c0k + quad * 8];
#pragma unroll
        for (int mt = 0; mt < 4; ++mt)
#pragma unroll
            for (int nt = 0; nt < 4; ++nt)
                acc[mt][nt] = __builtin_amdgcn_mfma_f32_16x16x32_bf16(
                    afr[mt], bfr[nt], acc[mt][nt], 0, 0, 0);
    }

#pragma unroll
    for (int mt = 0; mt < 4; ++mt) {
#pragma unroll
        for (int reg = 0; reg < 4; ++reg) {
            int rl = mt * 16 + quad * 4 + reg;
            float d0 = rowD[rl][0], d1 = rowD[rl][1], d2 = rowD[rl][2];
            float x0 = rowX[rl][0], x1 = rowX[rl][1], x2 = rowX[rl][2];
            int row = row0 + rl;
#pragma unroll
            for (int nt = 0; nt < 4; ++nt) {
                int col = wc + nt * 16 + l16;
                float v = acc[mt][nt][reg] + cl[col];
                v = fmaf(d0, m1l[col], v);
                v = fmaf(d1, m1l[256 + col], v);
                v = fmaf(d2, m1l[512 + col], v);
                v = fmaf(x0, m2l[col], v);
                v = fmaf(x1, m2l[256 + col], v);
                v = fmaf(x2, m2l[512 + col], v);
                size_t idx = (size_t)row * 256 + col;
                if (fp32out) ((float*)outv)[o3 + idx] = v;
                else         ((bf16*)outv)[o3 + idx] = __float2bfloat16(v);
                peB_out[idx] = f2b(v);
            }
        }
    }
}

// ---------------- generic MFMA level kernel (L2/L1/L0) ----------------
__global__ __launch_bounds__(256, 2) void level_mfma(
    const float* __restrict__ xyzf,
    const ushort_t* __restrict__ peB_prev,
    const int* __restrict__ kmap,
    const int* __restrict__ idxQ,
    const int* __restrict__ idxR,
    const float* __restrict__ M1, const float* __restrict__ M2,
    const float* __restrict__ cvec,
    const ushort_t* __restrict__ PT,
    const int* __restrict__ flag, void* __restrict__ outv, size_t out_off,
    ushort_t* __restrict__ peB_out) {
    __shared__ float m1l[768], m2l[768], cl[256];
    __shared__ float rowD[64][3], rowX[64][3];
    __shared__ int rowK[64];
    __shared__ __align__(16) ushort_t A_lds[64 * 264];

    int tid = threadIdx.x;
    int row0 = blockIdx.x * 64;
    int fp32out = flag[0];

    for (int i = tid; i < 768; i += 256) { m1l[i] = M1[i]; m2l[i] = M2[i]; }
    cl[tid] = cvec[tid];
    if (tid < 64) {
        int r = tid, row = row0 + r;
        float xx = xyzf[3 * row + 0];
        float yy = xyzf[3 * row + 1];
        float zz = xyzf[3 * row + 2];
        rowX[r][0] = xx; rowX[r][1] = yy; rowX[r][2] = zz;
        int k = kmap[row];
        rowK[r] = k;
        float qx = xx, qy = yy, qz = zz;
        if (idxQ) {
            int qi = idxQ[row];
            qx = xyzf[3 * qi + 0];
            qy = xyzf[3 * qi + 1];
            qz = xyzf[3 * qi + 2];
        }
        int ri = idxR[k];
        float rx = xyzf[3 * ri + 0];
        float ry = xyzf[3 * ri + 1];
        float rz = xyzf[3 * ri + 2];
        rowD[r][0] = qx - rx; rowD[r][1] = qy - ry; rowD[r][2] = qz - rz;
    }
    __syncthreads();

#pragma unroll
    for (int it = 0; it < 8; ++it) {
        int lin = it * 256 + tid;
        int r = lin >> 5, ch = lin & 31;
        *(uint4*)&A_lds[r * 264 + ch * 8] =
            *(const uint4*)(peB_prev + (size_t)rowK[r] * 256 + ch * 8);
    }
    __syncthreads();

    int wave = tid >> 6;
    int lane = tid & 63;
    int quad = lane >> 4;
    int l16 = lane & 15;
    int wc = wave * 64;

    const ushort_t* bbase[4];
#pragma unroll
    for (int nt = 0; nt < 4; ++nt)
        bbase[nt] = PT + (size_t)(wc + nt * 16 + l16) * 256 + quad * 8;

    float4v acc[4][4];
#pragma unroll
    for (int mt = 0; mt < 4; ++mt)
#pragma unroll
        for (int nt = 0; nt < 4; ++nt) acc[mt][nt] = (float4v){0.f, 0.f, 0.f, 0.f};

#pragma unroll
    for (int kt = 0; kt < 8; ++kt) {
        int c0 = kt * 32;
        short8 afr[4], bfr[4];
#pragma unroll
        for (int nt = 0; nt < 4; ++nt)
            bfr[nt] = *(const short8*)(bbase[nt] + c0);
#pragma unroll
        for (int mt = 0; mt < 4; ++mt)
            afr[mt] = *(const short8*)&A_lds[(mt * 16 + l16) * 264 + c0 + quad * 8];
#pragma unroll
        for (int mt = 0; mt < 4; ++mt)
#pragma unroll
            for (int nt = 0; nt < 4; ++nt)
                acc[mt][nt] = __builtin_amdgcn_mfma_f32_16x16x32_bf16(
                    afr[mt], bfr[nt], acc[mt][nt], 0, 0, 0);
    }

#pragma unroll
    for (int mt = 0; mt < 4; ++mt) {
#pragma unroll
        for (int reg = 0; reg < 4; ++reg) {
            int rl = mt * 16 + quad * 4 + reg;
            float d0 = rowD[rl][0], d1 = rowD[rl][1], d2 = rowD[rl][2];
            float x0 = rowX[rl][0], x1 = rowX[rl][1], x2 = rowX[rl][2];
            int row = row0 + rl;
#pragma unroll
            for (int nt = 0; nt < 4; ++nt) {
                int col = wc + nt * 16 + l16;
                float v = acc[mt][nt][reg] + cl[col];
                v = fmaf(d0, m1l[col], v);
                v = fmaf(d1, m1l[256 + col], v);
                v = fmaf(d2, m1l[512 + col], v);
                v = fmaf(x0, m2l[col], v);
                v = fmaf(x1, m2l[256 + col], v);
                v = fmaf(x2, m2l[512 + col], v);
                size_t idx = (size_t)row * 256 + col;
                if (fp32out) ((float*)outv)[out_off + idx] = v;
                else         ((bf16*)outv)[out_off + idx] = __float2bfloat16(v);
                if (peB_out) peB_out[idx] = f2b(v);
            }
        }
    }
}

extern "C" void kernel_launch(void* const* d_in, const int* in_sizes, int n_in,
                              void* d_out, int out_size, void* d_ws, size_t ws_size,
                              hipStream_t stream) {
    const int* idx0 = (const int*)d_in[1];
    const int* idx1 = (const int*)d_in[2];
    const int* idx2 = (const int*)d_in[3];
    const int* idx3 = (const int*)d_in[4];
    const int* idx4 = (const int*)d_in[5];

    // workspace layout (all offsets multiples of 64 floats => 16B aligned)
    float* ws = (float*)d_ws;
    int* flag = (int*)ws;            // 64 floats reserved
    float* p = ws + 64;
    float* xyzf = p;  p += 196608;
    float* Wallf = p; p += 768;
    float* ballf = p; p += 256;
    float* Wf0 = p;   p += 5 * 1024;          // (W 768 + b 256) x 5
    float* Pf0 = p;   p += 5 * 131328;        // (P 131072 + pb 256) x 5
    float* M1buf = p; p += 5 * 768;
    float* M2buf = p; p += 5 * 768;
    float* cbuf = p;  p += 5 * 256;
    int* k34 = (int*)p; p += 1024;
    int* k23 = (int*)p; p += 4096;
    int* k12 = (int*)p; p += 16384;
    ushort_t* pe3B = (ushort_t*)p; p += 131072;    // 1024*256 bf16
    ushort_t* pe2B = (ushort_t*)p; p += 524288;    // 4096*256 bf16
    ushort_t* pe1B = (ushort_t*)p; p += 2097152;   // 16384*256 bf16
    ushort_t* PTb = (ushort_t*)p;                  // 5 * 65536 bf16 (P_top^T only)

    CanonArgs ca;
    ca.src[0] = d_in[0];
    ca.src[1] = d_in[6];
    ca.src[2] = d_in[7];
    for (int i = 0; i < 10; ++i) ca.src[3 + i] = d_in[8 + i];
    for (int i = 0; i < 10; ++i) ca.src[13 + i] = d_in[18 + i];
    canon_kernel<<<3357, 256, 0, stream>>>(ca, flag, ws + 64);

    prep_nn_kernel<<<456, 512, 0, stream>>>(Pf0, Wf0, Wallf, ballf, xyzf,
                                            idx1, idx2, idx3, idx4,
                                            PTb, M1buf, M2buf, cbuf,
                                            k34, k23, k12);

    const size_t o4 = 0;
    const size_t o3 = (size_t)cN4 * 256;
    const size_t o2 = o3 + (size_t)cN3 * 256;
    const size_t o1 = o2 + (size_t)cN2 * 256;
    const size_t o0 = o1 + (size_t)cN1 * 256;

    level3_kernel<<<20, 256, 0, stream>>>(
        xyzf, idx3, idx4, k34,
        M1buf, M2buf, cbuf,
        M1buf + 768, M2buf + 768, cbuf + 256,
        PTb + 1 * 65536, flag, d_out, o4, o3, pe3B);

    level_mfma<<<cN2 / 64, 256, 0, stream>>>(
        xyzf, pe3B, k23, idx2, idx3, M1buf + 2 * 768, M2buf + 2 * 768, cbuf + 2 * 256,
        PTb + 2 * 65536, flag, d_out, o2, pe2B);
    level_mfma<<<cN1 / 64, 256, 0, stream>>>(
        xyzf, pe2B, k12, idx1, idx2, M1buf + 3 * 768, M2buf + 3 * 768, cbuf + 3 * 256,
        PTb + 3 * 65536, flag, d_out, o1, pe1B);
    level_mfma<<<cN0 / 64, 256, 0, stream>>>(
        xyzf, pe1B, idx0, nullptr, idx1, M1buf + 4 * 768, M2buf + 4 * 768, cbuf + 4 * 256,
        PTb + 4 * 65536, flag, d_out, o0, nullptr);
}